// Round 7
// baseline (90.462 us; speedup 1.0000x reference)
//
#include <hip/hip_runtime.h>

#define DEV __device__ __forceinline__

typedef __attribute__((ext_vector_type(4))) float f32x4;
typedef __bf16 bf16_t;
typedef __attribute__((ext_vector_type(4))) bf16_t bf16x4;
typedef __attribute__((ext_vector_type(8))) bf16_t bf16x8;
typedef __attribute__((ext_vector_type(8))) unsigned short us8;
typedef __attribute__((ext_vector_type(4))) unsigned short us4;

// B=8, S=2048, D_MODEL=256, H=4, DEPTH=64, BH=32, M=B*S=16384

DEV unsigned short f2bf(float f) {
  bf16_t h = (bf16_t)f;
  return __builtin_bit_cast(unsigned short, h);
}

DEV void gl2lds16(const void* g, void* l) {
  __builtin_amdgcn_global_load_lds(
      (const __attribute__((address_space(1))) unsigned int*)g,
      (__attribute__((address_space(3))) unsigned int*)l, 16, 0, 0);
}

DEV f32x4 mfma16(bf16x8 a, bf16x8 b, f32x4 c) {
  return __builtin_amdgcn_mfma_f32_16x16x32_bf16(a, b, c, 0, 0, 0);
}

// ---- prep: W transpose via LDS (blocks 0..63), mask prescale + prune (block 64) ----
// Pruning: tile t of batch b can influence softmax only if
//   tilemin_mask[t] < running_min + 1.45e-6   (sound bound, |0.18*qk|<=1000)
__global__ __launch_bounds__(256) void prep_w(
    const float* __restrict__ wq, const float* __restrict__ wk,
    const float* __restrict__ wv, const float* __restrict__ wo,
    const float* __restrict__ mask,
    unsigned short* __restrict__ wt, float* __restrict__ mprep,
    int* __restrict__ proc) {
  const int t = threadIdx.x;
  if (blockIdx.x < 64) {
    __shared__ float T[64 * 65];
    const int mat = blockIdx.x >> 4, tn = (blockIdx.x >> 2) & 3, tk = blockIdx.x & 3;
    const int n0 = tn * 64, k0 = tk * 64;
    const float* W = (mat == 0) ? wq : (mat == 1) ? wk : (mat == 2) ? wv : wo;
    const int r0 = t >> 4, c = (t & 15) * 4;
#pragma unroll
    for (int i = 0; i < 4; ++i) {
      int rr = r0 + i * 16;                       // k-local row
      f32x4 x = *(const f32x4*)(W + (k0 + rr) * 256 + n0 + c);
#pragma unroll
      for (int j = 0; j < 4; ++j) T[(c + j) * 65 + rr] = x[j];
    }
    __syncthreads();
#pragma unroll
    for (int i = 0; i < 2; ++i) {
      int u = t + i * 256;
      int n = u >> 3, seg = u & 7;
      us8 pk;
#pragma unroll
      for (int j = 0; j < 8; ++j) pk[j] = f2bf(T[n * 65 + seg * 8 + j]);
      *(us8*)(&wt[mat * 65536 + (n0 + n) * 256 + k0 + seg * 8]) = pk;
    }
  } else {
    __shared__ float tm[256];
    const float* mr = mask + t * 64;
    float mn = 1e30f;
#pragma unroll
    for (int j = 0; j < 16; ++j) {
      f32x4 x = *(const f32x4*)(mr + j * 4);
      mn = fminf(mn, fminf(fminf(x[0], x[1]), fminf(x[2], x[3])));
      *(f32x4*)(mprep + t * 64 + j * 4) = x * -1.442695041e9f;
    }
    tm[t] = mn;
    __syncthreads();
    if (t < 8) {
      int base = t * 33, cnt = 0;
      float minm = 1e30f;
      for (int tl = 0; tl < 32; ++tl) {
        float v = tm[t * 32 + tl];
        if (v < minm + 1.45e-6f) { proc[base + 1 + cnt] = tl; ++cnt; }
        minm = fminf(minm, v);
      }
      proc[base] = cnt;
    }
  }
}

// ---- QKV projection: register-resident B, zero-LDS, runtime strip loop ----
// Each wave owns 64 output cols (one head); full-K B-frags (128 VGPR) hoisted
// out of a NON-unrolled 4-strip loop so LICM keeps them resident.
__global__ __launch_bounds__(256, 2) void gemm_qkv(
    const float* __restrict__ Aq, const float* __restrict__ Ak, const float* __restrict__ Av,
    const float* __restrict__ bq, const float* __restrict__ bk, const float* __restrict__ bv,
    const unsigned short* __restrict__ wt,
    unsigned short* __restrict__ Qh, unsigned short* __restrict__ Kh,
    unsigned short* __restrict__ VhT) {
  const int p = blockIdx.y;
  const float* A    = (p == 0) ? Aq : (p == 1) ? Ak : Av;
  const float* bias = (p == 0) ? bq : (p == 1) ? bk : bv;
  const unsigned short* WT = wt + p * 65536;
  const int t = threadIdx.x, lane = t & 63, wvi = t >> 6;
  const int lr = lane & 15, lg = lane >> 4;
  const int n0 = wvi * 64;

  // B fragments: bfr[cg][ds] = W[k=ds*32+lg*8+j][col=n0+cg*16+lr]  (invariant)
  bf16x8 bfr[4][8];
#pragma unroll
  for (int cg = 0; cg < 4; ++cg) {
    const unsigned short* wr = WT + (n0 + cg * 16 + lr) * 256 + lg * 8;
#pragma unroll
    for (int ds = 0; ds < 8; ++ds)
      bfr[cg][ds] = *(const bf16x8*)(wr + ds * 32);
  }
  float bb[4];
#pragma unroll
  for (int cg = 0; cg < 4; ++cg) bb[cg] = bias[n0 + cg * 16 + lr];

#pragma unroll 1
  for (int i = 0; i < 4; ++i) {
    const int strip = blockIdx.x + i * 256;      // 0..1023
    const int m0 = strip * 16;
    const int b = m0 >> 11, s0 = m0 & 2047;
    const int bh = b * 4 + wvi;                  // wave's head
    const float* ap = A + (m0 + lr) * 256 + lg * 8;
    bf16x8 af[8];
#pragma unroll
    for (int ds = 0; ds < 8; ++ds) {
      f32x4 x0 = *(const f32x4*)(ap + ds * 32);
      f32x4 x1 = *(const f32x4*)(ap + ds * 32 + 4);
      bf16x8 a;
#pragma unroll
      for (int j = 0; j < 4; ++j) { a[j] = (bf16_t)x0[j]; a[j + 4] = (bf16_t)x1[j]; }
      af[ds] = a;
    }
    f32x4 acc[4] = {};
#pragma unroll
    for (int cg = 0; cg < 4; ++cg)
#pragma unroll
      for (int ds = 0; ds < 8; ++ds)
        acc[cg] = mfma16(af[ds], bfr[cg][ds], acc[cg]);

    if (p == 2) {
#pragma unroll
      for (int cg = 0; cg < 4; ++cg) {
        int d = cg * 16 + lr;
        us4 o;
#pragma unroll
        for (int r = 0; r < 4; ++r) o[r] = f2bf(acc[cg][r] + bb[cg]);
        *(us4*)(&VhT[(bh * 64 + d) * 2048 + s0 + lg * 4]) = o;
      }
    } else {
      unsigned short* Cp = (p == 0) ? Qh : Kh;
#pragma unroll
      for (int cg = 0; cg < 4; ++cg) {
        int d = cg * 16 + lr;
#pragma unroll
        for (int r = 0; r < 4; ++r)
          Cp[(bh * 2048 + s0 + lg * 4 + r) * 64 + d] = f2bf(acc[cg][r] + bb[cg]);
      }
    }
  }
}

// ---- fused flash attention: pruned tile list, swapped QK^T, in-register P ----
__global__ __launch_bounds__(256) void attn(
    const unsigned short* __restrict__ Qh, const unsigned short* __restrict__ Kh,
    const unsigned short* __restrict__ VhT, const float* __restrict__ mprep,
    const int* __restrict__ proc,
    unsigned short* __restrict__ Aout) {
  __shared__ __align__(16) unsigned short Kt[2][4096];
  __shared__ __align__(16) unsigned short Vt[2][4096];
  const int bh = blockIdx.y;
  const int q0 = blockIdx.x * 64;
  const int t = threadIdx.x, lane = t & 63, wid = t >> 6;
  const int lr = lane & 15, lg = lane >> 4;
  const int qrow = q0 + wid * 16;
  const unsigned short* Kbase = Kh + bh * 131072;
  const unsigned short* Vbase = VhT + bh * 131072;
  const float* mrow = mprep + (bh >> 2) * 2048;
  const int* plist = proc + (bh >> 2) * 33;
  const int lx = lr & 7;          // swizzle xor
  const int lgh = lg >> 1, lgo = (lg & 1) * 4;

  bf16x8 qf[2];
#pragma unroll
  for (int ds = 0; ds < 2; ++ds)
    qf[ds] = *(const bf16x8*)(Qh + (bh * 2048 + qrow + lr) * 64 + ds * 32 + lg * 8);

  f32x4 accO[4] = {};           // accO[db][r] = O[q=lr][d=db*16+lg*4+r]
  float mrun = -3.0e38f, lrun = 0.f;

#define STAGE(buf, kv)                                                        \
  {                                                                           \
    _Pragma("unroll")                                                         \
    for (int i = 0; i < 2; ++i) {                                             \
      int u = t + i * 256;                                                    \
      int row = u >> 3, g = (u & 7) ^ (row & 7);                              \
      gl2lds16(Kbase + ((kv) + row) * 64 + g * 8, &Kt[buf][u * 8]);           \
      gl2lds16(Vbase + row * 2048 + (kv) + g * 8, &Vt[buf][u * 8]);           \
    }                                                                         \
  }

  const int cnt = plist[0];                 // block-uniform
  STAGE(0, plist[1] * 64)
  __syncthreads();
  int cur = 0;

  for (int j = 0; j < cnt; ++j) {
    const int kv0 = plist[1 + j] * 64;
    if (j + 1 < cnt) STAGE(cur ^ 1, plist[2 + j] * 64)

    // S^T = K Q^T : accS[kb][r] = S[q=lr][k = kv0 + kb*16 + lg*4 + r]
    f32x4 accS[4] = {};
    __builtin_amdgcn_s_setprio(1);
#pragma unroll
    for (int kb = 0; kb < 4; ++kb)
#pragma unroll
      for (int ds = 0; ds < 2; ++ds) {
        bf16x8 kf = *(const bf16x8*)(&Kt[cur][((kb * 16 + lr) << 3 | (((ds << 2) | lg) ^ lx)) * 8]);
        accS[kb] = mfma16(kf, qf[ds], accS[kb]);
      }
    __builtin_amdgcn_s_setprio(0);

    // logits in log2 domain (per-lane row q=lr)
    f32x4 sv[4];
#pragma unroll
    for (int kb = 0; kb < 4; ++kb) {
      f32x4 mk = *(const f32x4*)(mrow + kv0 + kb * 16 + lg * 4);
      sv[kb] = accS[kb] * 0.1803368801f + mk;
    }
    float mx0 = fmaxf(fmaxf(sv[0][0], sv[0][1]), fmaxf(sv[0][2], sv[0][3]));
    float mx1 = fmaxf(fmaxf(sv[1][0], sv[1][1]), fmaxf(sv[1][2], sv[1][3]));
    float mx2 = fmaxf(fmaxf(sv[2][0], sv[2][1]), fmaxf(sv[2][2], sv[2][3]));
    float mx3 = fmaxf(fmaxf(sv[3][0], sv[3][1]), fmaxf(sv[3][2], sv[3][3]));
    float mx = fmaxf(fmaxf(mx0, mx1), fmaxf(mx2, mx3));
    mx = fmaxf(mx, __shfl_xor(mx, 16));
    mx = fmaxf(mx, __shfl_xor(mx, 32));
    float mnew = fmaxf(mrun, mx);
    float al = __builtin_amdgcn_exp2f(mrun - mnew);
    mrun = mnew;

    float px[4][4];
    float lsum = 0.f;
#pragma unroll
    for (int kb = 0; kb < 4; ++kb) {
      float s = 0.f;
#pragma unroll
      for (int r = 0; r < 4; ++r) {
        px[kb][r] = __builtin_amdgcn_exp2f(sv[kb][r] - mnew);
        s += px[kb][r];
      }
      lsum += s;
    }
    lsum += __shfl_xor(lsum, 16);
    lsum += __shfl_xor(lsum, 32);
    lrun = lrun * al + lsum;
#pragma unroll
    for (int db = 0; db < 4; ++db) accO[db] *= al;

    // P fragments, fully lane-local (k-permutation matched by V reads)
    bf16x8 pf[2];
#pragma unroll
    for (int ks = 0; ks < 2; ++ks) {
      bf16x8 p;
#pragma unroll
      for (int r = 0; r < 4; ++r) {
        p[r]     = (bf16_t)px[2 * ks][r];
        p[r + 4] = (bf16_t)px[2 * ks + 1][r];
      }
      pf[ks] = p;
    }

    // O^T += V^T P^T   (A = V^T rows d, k permuted; B = pf)
    __builtin_amdgcn_s_setprio(1);
#pragma unroll
    for (int ks = 0; ks < 2; ++ks)
#pragma unroll
      for (int db = 0; db < 4; ++db) {
        int row = db * 16 + lr;
        int u0 = (row << 3) | (((ks << 2) | lgh) ^ lx);
        int u1 = (row << 3) | (((ks << 2) | 2 | lgh) ^ lx);
        bf16x4 v0 = *(const bf16x4*)(&Vt[cur][u0 * 8 + lgo]);
        bf16x4 v1 = *(const bf16x4*)(&Vt[cur][u1 * 8 + lgo]);
        bf16x8 vf = __builtin_shufflevector(v0, v1, 0, 1, 2, 3, 4, 5, 6, 7);
        accO[db] = mfma16(vf, pf[ks], accO[db]);
      }
    __builtin_amdgcn_s_setprio(0);

    __syncthreads();   // drains prefetch vmcnt + releases cur buf
    cur ^= 1;
  }
#undef STAGE

  const int b = bh >> 2, h = bh & 3;
  const float inv = __builtin_amdgcn_rcpf(lrun);
  const int q = qrow + lr;
#pragma unroll
  for (int db = 0; db < 4; ++db) {
    us4 o;
#pragma unroll
    for (int r = 0; r < 4; ++r) o[r] = f2bf(accO[db][r] * inv);
    *(us4*)(&Aout[(b * 2048 + q) * 256 + h * 64 + db * 16 + lg * 4]) = o;
  }
}

// ---- output projection: register-resident B, runtime strip loop, f32 out ----
__global__ __launch_bounds__(256, 2) void gemm_out(
    const unsigned short* __restrict__ Aout, const unsigned short* __restrict__ wt,
    const float* __restrict__ bo, float* __restrict__ out) {
  const unsigned short* WT = wt + 3 * 65536;
  const int t = threadIdx.x, lane = t & 63, wvi = t >> 6;
  const int lr = lane & 15, lg = lane >> 4;
  const int n0 = wvi * 64;

  bf16x8 bfr[4][8];
#pragma unroll
  for (int cg = 0; cg < 4; ++cg) {
    const unsigned short* wr = WT + (n0 + cg * 16 + lr) * 256 + lg * 8;
#pragma unroll
    for (int ds = 0; ds < 8; ++ds)
      bfr[cg][ds] = *(const bf16x8*)(wr + ds * 32);
  }
  float bb[4];
#pragma unroll
  for (int cg = 0; cg < 4; ++cg) bb[cg] = bo[n0 + cg * 16 + lr];

#pragma unroll 1
  for (int i = 0; i < 2; ++i) {
    const int strip = blockIdx.x + i * 512;      // 0..1023
    const int m0 = strip * 16;
    const unsigned short* ap = Aout + (m0 + lr) * 256 + lg * 8;
    bf16x8 af[8];
#pragma unroll
    for (int ds = 0; ds < 8; ++ds)
      af[ds] = *(const bf16x8*)(ap + ds * 32);
    f32x4 acc[4] = {};
#pragma unroll
    for (int cg = 0; cg < 4; ++cg)
#pragma unroll
      for (int ds = 0; ds < 8; ++ds)
        acc[cg] = mfma16(af[ds], bfr[cg][ds], acc[cg]);
#pragma unroll
    for (int cg = 0; cg < 4; ++cg) {
      int col = n0 + cg * 16 + lr;
#pragma unroll
      for (int r = 0; r < 4; ++r)
        out[(m0 + lg * 4 + r) * 256 + col] = acc[cg][r] + bb[cg];
    }
  }
}

extern "C" void kernel_launch(void* const* d_in, const int* in_sizes, int n_in,
                              void* d_out, int out_size, void* d_ws, size_t ws_size,
                              hipStream_t stream) {
  const float* v    = (const float*)d_in[0];
  const float* k    = (const float*)d_in[1];
  const float* q    = (const float*)d_in[2];
  const float* mask = (const float*)d_in[3];
  const float* wq   = (const float*)d_in[4];
  const float* bq   = (const float*)d_in[5];
  const float* wk   = (const float*)d_in[6];
  const float* bk   = (const float*)d_in[7];
  const float* wv   = (const float*)d_in[8];
  const float* bv   = (const float*)d_in[9];
  const float* wo   = (const float*)d_in[10];
  const float* bo   = (const float*)d_in[11];
  float* out = (float*)d_out;
  char* ws = (char*)d_ws;

  // ws: wt 524288 | mprep 65536 | proc 4096 | Qh | Kh | VhT | Aout (8 MB each)
  unsigned short* wt  = (unsigned short*)(ws);
  float*          mp  = (float*)(ws + 524288);
  int*            pr  = (int*)(ws + 589824);
  unsigned short* Qh  = (unsigned short*)(ws + 593920);
  unsigned short* Kh  = (unsigned short*)(ws + 593920 + 8388608);
  unsigned short* VhT = (unsigned short*)(ws + 593920 + 2 * 8388608);
  unsigned short* Ao  = (unsigned short*)(ws + 593920 + 3 * 8388608);

  prep_w<<<dim3(65), dim3(256), 0, stream>>>(wq, wk, wv, wo, mask, wt, mp, pr);
  gemm_qkv<<<dim3(256, 3), dim3(256), 0, stream>>>(q, k, v, bq, bk, bv, wt, Qh, Kh, VhT);
  attn<<<dim3(32, 32), dim3(256), 0, stream>>>(Qh, Kh, VhT, mp, pr, Ao);
  gemm_out<<<dim3(512), dim3(256), 0, stream>>>(Ao, wt, bo, out);
}

// Round 8
// 88.076 us; speedup vs baseline: 1.0271x; 1.0271x over previous
//
#include <hip/hip_runtime.h>

#define DEV __device__ __forceinline__

typedef __attribute__((ext_vector_type(4))) float f32x4;
typedef __bf16 bf16_t;
typedef __attribute__((ext_vector_type(4))) bf16_t bf16x4;
typedef __attribute__((ext_vector_type(8))) bf16_t bf16x8;
typedef __attribute__((ext_vector_type(8))) unsigned short us8;
typedef __attribute__((ext_vector_type(4))) unsigned short us4;

// B=8, S=2048, D_MODEL=256, H=4, DEPTH=64, BH=32, M=B*S=16384

DEV unsigned short f2bf(float f) {
  bf16_t h = (bf16_t)f;
  return __builtin_bit_cast(unsigned short, h);
}

DEV void gl2lds16(const void* g, void* l) {
  __builtin_amdgcn_global_load_lds(
      (const __attribute__((address_space(1))) unsigned int*)g,
      (__attribute__((address_space(3))) unsigned int*)l, 16, 0, 0);
}

DEV f32x4 mfma16(bf16x8 a, bf16x8 b, f32x4 c) {
  return __builtin_amdgcn_mfma_f32_16x16x32_bf16(a, b, c, 0, 0, 0);
}

// ---- prep: W transpose via LDS (blocks 0..63), mask prescale + prune (block 64) ----
// Pruning: tile t of batch b can influence softmax only if
//   tilemin_mask[t] < running_min + 1.45e-6   (sound bound, |0.18*qk|<=1000)
__global__ __launch_bounds__(256) void prep_w(
    const float* __restrict__ wq, const float* __restrict__ wk,
    const float* __restrict__ wv, const float* __restrict__ wo,
    const float* __restrict__ mask,
    unsigned short* __restrict__ wt, float* __restrict__ mprep,
    int* __restrict__ proc) {
  const int t = threadIdx.x;
  if (blockIdx.x < 64) {
    __shared__ float T[64 * 65];
    const int mat = blockIdx.x >> 4, tn = (blockIdx.x >> 2) & 3, tk = blockIdx.x & 3;
    const int n0 = tn * 64, k0 = tk * 64;
    const float* W = (mat == 0) ? wq : (mat == 1) ? wk : (mat == 2) ? wv : wo;
    const int r0 = t >> 4, c = (t & 15) * 4;
#pragma unroll
    for (int i = 0; i < 4; ++i) {
      int rr = r0 + i * 16;                       // k-local row
      f32x4 x = *(const f32x4*)(W + (k0 + rr) * 256 + n0 + c);
#pragma unroll
      for (int j = 0; j < 4; ++j) T[(c + j) * 65 + rr] = x[j];
    }
    __syncthreads();
#pragma unroll
    for (int i = 0; i < 2; ++i) {
      int u = t + i * 256;
      int n = u >> 3, seg = u & 7;
      us8 pk;
#pragma unroll
      for (int j = 0; j < 8; ++j) pk[j] = f2bf(T[n * 65 + seg * 8 + j]);
      *(us8*)(&wt[mat * 65536 + (n0 + n) * 256 + k0 + seg * 8]) = pk;
    }
  } else {
    __shared__ float tm[256];
    const float* mr = mask + t * 64;
    float mn = 1e30f;
#pragma unroll
    for (int j = 0; j < 16; ++j) {
      f32x4 x = *(const f32x4*)(mr + j * 4);
      mn = fminf(mn, fminf(fminf(x[0], x[1]), fminf(x[2], x[3])));
      *(f32x4*)(mprep + t * 64 + j * 4) = x * -1.442695041e9f;
    }
    tm[t] = mn;
    __syncthreads();
    if (t < 8) {
      int base = t * 33, cnt = 0;
      float minm = 1e30f;
      for (int tl = 0; tl < 32; ++tl) {
        float v = tm[t * 32 + tl];
        if (v < minm + 1.45e-6f) { proc[base + 1 + cnt] = tl; ++cnt; }
        minm = fminf(minm, v);
      }
      proc[base] = cnt;
    }
  }
}

// ---- QKV projection: register-resident B (asm-pinned), zero-LDS streaming ----
// Each wave owns 64 output cols (one head); full-K B-frags (128 VGPR) loaded
// once and pinned via opaque asm so the allocator cannot rematerialize them.
__global__ __launch_bounds__(256, 2) void gemm_qkv(
    const float* __restrict__ Aq, const float* __restrict__ Ak, const float* __restrict__ Av,
    const float* __restrict__ bq, const float* __restrict__ bk, const float* __restrict__ bv,
    const unsigned short* __restrict__ wt,
    unsigned short* __restrict__ Qh, unsigned short* __restrict__ Kh,
    unsigned short* __restrict__ VhT) {
  const int p = blockIdx.y;
  const float* A    = (p == 0) ? Aq : (p == 1) ? Ak : Av;
  const float* bias = (p == 0) ? bq : (p == 1) ? bk : bv;
  const unsigned short* WT = wt + p * 65536;
  const int t = threadIdx.x, lane = t & 63, wvi = t >> 6;
  const int lr = lane & 15, lg = lane >> 4;
  const int n0 = wvi * 64;

  // B fragments: bfr[cg][ds] = W[k=ds*32+lg*8+j][col=n0+cg*16+lr]  (invariant)
  bf16x8 bfr[4][8];
#pragma unroll
  for (int cg = 0; cg < 4; ++cg) {
    const unsigned short* wr = WT + (n0 + cg * 16 + lr) * 256 + lg * 8;
#pragma unroll
    for (int ds = 0; ds < 8; ++ds)
      bfr[cg][ds] = *(const bf16x8*)(wr + ds * 32);
  }
  // PIN: opaque op makes these unrematerializable -> must stay in VGPRs.
#pragma unroll
  for (int cg = 0; cg < 4; ++cg)
#pragma unroll
    for (int ds = 0; ds < 8; ++ds)
      asm volatile("" : "+v"(bfr[cg][ds]));

  float bb[4];
#pragma unroll
  for (int cg = 0; cg < 4; ++cg) bb[cg] = bias[n0 + cg * 16 + lr];

#pragma unroll 1
  for (int i = 0; i < 4; ++i) {
    const int strip = blockIdx.x + i * 256;      // 0..1023
    const int m0 = strip * 16;
    const int b = m0 >> 11, s0 = m0 & 2047;
    const int bh = b * 4 + wvi;                  // wave's head
    const float* ap = A + (m0 + lr) * 256 + lg * 8;
    bf16x8 af[8];
#pragma unroll
    for (int ds = 0; ds < 8; ++ds) {
      f32x4 x0 = *(const f32x4*)(ap + ds * 32);
      f32x4 x1 = *(const f32x4*)(ap + ds * 32 + 4);
      bf16x8 a;
#pragma unroll
      for (int j = 0; j < 4; ++j) { a[j] = (bf16_t)x0[j]; a[j + 4] = (bf16_t)x1[j]; }
      af[ds] = a;
    }
    f32x4 acc[4] = {};
#pragma unroll
    for (int cg = 0; cg < 4; ++cg)
#pragma unroll
      for (int ds = 0; ds < 8; ++ds)
        acc[cg] = mfma16(af[ds], bfr[cg][ds], acc[cg]);

    if (p == 2) {
#pragma unroll
      for (int cg = 0; cg < 4; ++cg) {
        int d = cg * 16 + lr;
        us4 o;
#pragma unroll
        for (int r = 0; r < 4; ++r) o[r] = f2bf(acc[cg][r] + bb[cg]);
        *(us4*)(&VhT[(bh * 64 + d) * 2048 + s0 + lg * 4]) = o;
      }
    } else {
      unsigned short* Cp = (p == 0) ? Qh : Kh;
#pragma unroll
      for (int cg = 0; cg < 4; ++cg) {
        int d = cg * 16 + lr;
#pragma unroll
        for (int r = 0; r < 4; ++r)
          Cp[(bh * 2048 + s0 + lg * 4 + r) * 64 + d] = f2bf(acc[cg][r] + bb[cg]);
      }
    }
  }
}

// ---- fused flash attention: pruned tile list, swapped QK^T, in-register P ----
__global__ __launch_bounds__(256) void attn(
    const unsigned short* __restrict__ Qh, const unsigned short* __restrict__ Kh,
    const unsigned short* __restrict__ VhT, const float* __restrict__ mprep,
    const int* __restrict__ proc,
    unsigned short* __restrict__ Aout) {
  __shared__ __align__(16) unsigned short Kt[2][4096];
  __shared__ __align__(16) unsigned short Vt[2][4096];
  const int bh = blockIdx.y;
  const int q0 = blockIdx.x * 64;
  const int t = threadIdx.x, lane = t & 63, wid = t >> 6;
  const int lr = lane & 15, lg = lane >> 4;
  const int qrow = q0 + wid * 16;
  const unsigned short* Kbase = Kh + bh * 131072;
  const unsigned short* Vbase = VhT + bh * 131072;
  const float* mrow = mprep + (bh >> 2) * 2048;
  const int* plist = proc + (bh >> 2) * 33;
  const int lx = lr & 7;          // swizzle xor
  const int lgh = lg >> 1, lgo = (lg & 1) * 4;

  bf16x8 qf[2];
#pragma unroll
  for (int ds = 0; ds < 2; ++ds)
    qf[ds] = *(const bf16x8*)(Qh + (bh * 2048 + qrow + lr) * 64 + ds * 32 + lg * 8);

  f32x4 accO[4] = {};           // accO[db][r] = O[q=lr][d=db*16+lg*4+r]
  float mrun = -3.0e38f, lrun = 0.f;

#define STAGE(buf, kv)                                                        \
  {                                                                           \
    _Pragma("unroll")                                                         \
    for (int i = 0; i < 2; ++i) {                                             \
      int u = t + i * 256;                                                    \
      int row = u >> 3, g = (u & 7) ^ (row & 7);                              \
      gl2lds16(Kbase + ((kv) + row) * 64 + g * 8, &Kt[buf][u * 8]);           \
      gl2lds16(Vbase + row * 2048 + (kv) + g * 8, &Vt[buf][u * 8]);           \
    }                                                                         \
  }

  const int cnt = plist[0];                 // block-uniform
  STAGE(0, plist[1] * 64)
  __syncthreads();
  int cur = 0;

  for (int j = 0; j < cnt; ++j) {
    const int kv0 = plist[1 + j] * 64;
    if (j + 1 < cnt) STAGE(cur ^ 1, plist[2 + j] * 64)

    // S^T = K Q^T : accS[kb][r] = S[q=lr][k = kv0 + kb*16 + lg*4 + r]
    f32x4 accS[4] = {};
    __builtin_amdgcn_s_setprio(1);
#pragma unroll
    for (int kb = 0; kb < 4; ++kb)
#pragma unroll
      for (int ds = 0; ds < 2; ++ds) {
        bf16x8 kf = *(const bf16x8*)(&Kt[cur][((kb * 16 + lr) << 3 | (((ds << 2) | lg) ^ lx)) * 8]);
        accS[kb] = mfma16(kf, qf[ds], accS[kb]);
      }
    __builtin_amdgcn_s_setprio(0);

    // logits in log2 domain (per-lane row q=lr)
    f32x4 sv[4];
#pragma unroll
    for (int kb = 0; kb < 4; ++kb) {
      f32x4 mk = *(const f32x4*)(mrow + kv0 + kb * 16 + lg * 4);
      sv[kb] = accS[kb] * 0.1803368801f + mk;
    }
    float mx0 = fmaxf(fmaxf(sv[0][0], sv[0][1]), fmaxf(sv[0][2], sv[0][3]));
    float mx1 = fmaxf(fmaxf(sv[1][0], sv[1][1]), fmaxf(sv[1][2], sv[1][3]));
    float mx2 = fmaxf(fmaxf(sv[2][0], sv[2][1]), fmaxf(sv[2][2], sv[2][3]));
    float mx3 = fmaxf(fmaxf(sv[3][0], sv[3][1]), fmaxf(sv[3][2], sv[3][3]));
    float mx = fmaxf(fmaxf(mx0, mx1), fmaxf(mx2, mx3));
    mx = fmaxf(mx, __shfl_xor(mx, 16));
    mx = fmaxf(mx, __shfl_xor(mx, 32));
    float mnew = fmaxf(mrun, mx);
    float al = __builtin_amdgcn_exp2f(mrun - mnew);
    mrun = mnew;

    float px[4][4];
    float lsum = 0.f;
#pragma unroll
    for (int kb = 0; kb < 4; ++kb) {
      float s = 0.f;
#pragma unroll
      for (int r = 0; r < 4; ++r) {
        px[kb][r] = __builtin_amdgcn_exp2f(sv[kb][r] - mnew);
        s += px[kb][r];
      }
      lsum += s;
    }
    lsum += __shfl_xor(lsum, 16);
    lsum += __shfl_xor(lsum, 32);
    lrun = lrun * al + lsum;
#pragma unroll
    for (int db = 0; db < 4; ++db) accO[db] *= al;

    // P fragments, fully lane-local (k-permutation matched by V reads)
    bf16x8 pf[2];
#pragma unroll
    for (int ks = 0; ks < 2; ++ks) {
      bf16x8 p;
#pragma unroll
      for (int r = 0; r < 4; ++r) {
        p[r]     = (bf16_t)px[2 * ks][r];
        p[r + 4] = (bf16_t)px[2 * ks + 1][r];
      }
      pf[ks] = p;
    }

    // O^T += V^T P^T   (A = V^T rows d, k permuted; B = pf)
    __builtin_amdgcn_s_setprio(1);
#pragma unroll
    for (int ks = 0; ks < 2; ++ks)
#pragma unroll
      for (int db = 0; db < 4; ++db) {
        int row = db * 16 + lr;
        int u0 = (row << 3) | (((ks << 2) | lgh) ^ lx);
        int u1 = (row << 3) | (((ks << 2) | 2 | lgh) ^ lx);
        bf16x4 v0 = *(const bf16x4*)(&Vt[cur][u0 * 8 + lgo]);
        bf16x4 v1 = *(const bf16x4*)(&Vt[cur][u1 * 8 + lgo]);
        bf16x8 vf = __builtin_shufflevector(v0, v1, 0, 1, 2, 3, 4, 5, 6, 7);
        accO[db] = mfma16(vf, pf[ks], accO[db]);
      }
    __builtin_amdgcn_s_setprio(0);

    __syncthreads();   // drains prefetch vmcnt + releases cur buf
    cur ^= 1;
  }
#undef STAGE

  const int b = bh >> 2, h = bh & 3;
  const float inv = __builtin_amdgcn_rcpf(lrun);
  const int q = qrow + lr;
#pragma unroll
  for (int db = 0; db < 4; ++db) {
    us4 o;
#pragma unroll
    for (int r = 0; r < 4; ++r) o[r] = f2bf(accO[db][r] * inv);
    *(us4*)(&Aout[(b * 2048 + q) * 256 + h * 64 + db * 16 + lg * 4]) = o;
  }
}

// ---- output projection: register-resident B (asm-pinned), f32 out ----
__global__ __launch_bounds__(256, 2) void gemm_out(
    const unsigned short* __restrict__ Aout, const unsigned short* __restrict__ wt,
    const float* __restrict__ bo, float* __restrict__ out) {
  const unsigned short* WT = wt + 3 * 65536;
  const int t = threadIdx.x, lane = t & 63, wvi = t >> 6;
  const int lr = lane & 15, lg = lane >> 4;
  const int n0 = wvi * 64;

  bf16x8 bfr[4][8];
#pragma unroll
  for (int cg = 0; cg < 4; ++cg) {
    const unsigned short* wr = WT + (n0 + cg * 16 + lr) * 256 + lg * 8;
#pragma unroll
    for (int ds = 0; ds < 8; ++ds)
      bfr[cg][ds] = *(const bf16x8*)(wr + ds * 32);
  }
#pragma unroll
  for (int cg = 0; cg < 4; ++cg)
#pragma unroll
    for (int ds = 0; ds < 8; ++ds)
      asm volatile("" : "+v"(bfr[cg][ds]));

  float bb[4];
#pragma unroll
  for (int cg = 0; cg < 4; ++cg) bb[cg] = bo[n0 + cg * 16 + lr];

#pragma unroll 1
  for (int i = 0; i < 2; ++i) {
    const int strip = blockIdx.x + i * 512;      // 0..1023
    const int m0 = strip * 16;
    const unsigned short* ap = Aout + (m0 + lr) * 256 + lg * 8;
    bf16x8 af[8];
#pragma unroll
    for (int ds = 0; ds < 8; ++ds)
      af[ds] = *(const bf16x8*)(ap + ds * 32);
    f32x4 acc[4] = {};
#pragma unroll
    for (int cg = 0; cg < 4; ++cg)
#pragma unroll
      for (int ds = 0; ds < 8; ++ds)
        acc[cg] = mfma16(af[ds], bfr[cg][ds], acc[cg]);
#pragma unroll
    for (int cg = 0; cg < 4; ++cg) {
      int col = n0 + cg * 16 + lr;
#pragma unroll
      for (int r = 0; r < 4; ++r)
        out[(m0 + lg * 4 + r) * 256 + col] = acc[cg][r] + bb[cg];
    }
  }
}

extern "C" void kernel_launch(void* const* d_in, const int* in_sizes, int n_in,
                              void* d_out, int out_size, void* d_ws, size_t ws_size,
                              hipStream_t stream) {
  const float* v    = (const float*)d_in[0];
  const float* k    = (const float*)d_in[1];
  const float* q    = (const float*)d_in[2];
  const float* mask = (const float*)d_in[3];
  const float* wq   = (const float*)d_in[4];
  const float* bq   = (const float*)d_in[5];
  const float* wk   = (const float*)d_in[6];
  const float* bk   = (const float*)d_in[7];
  const float* wv   = (const float*)d_in[8];
  const float* bv   = (const float*)d_in[9];
  const float* wo   = (const float*)d_in[10];
  const float* bo   = (const float*)d_in[11];
  float* out = (float*)d_out;
  char* ws = (char*)d_ws;

  // ws: wt 524288 | mprep 65536 | proc 4096 | Qh | Kh | VhT | Aout (8 MB each)
  unsigned short* wt  = (unsigned short*)(ws);
  float*          mp  = (float*)(ws + 524288);
  int*            pr  = (int*)(ws + 589824);
  unsigned short* Qh  = (unsigned short*)(ws + 593920);
  unsigned short* Kh  = (unsigned short*)(ws + 593920 + 8388608);
  unsigned short* VhT = (unsigned short*)(ws + 593920 + 2 * 8388608);
  unsigned short* Ao  = (unsigned short*)(ws + 593920 + 3 * 8388608);

  prep_w<<<dim3(65), dim3(256), 0, stream>>>(wq, wk, wv, wo, mask, wt, mp, pr);
  gemm_qkv<<<dim3(256, 3), dim3(256), 0, stream>>>(q, k, v, bq, bk, bv, wt, Qh, Kh, VhT);
  attn<<<dim3(32, 32), dim3(256), 0, stream>>>(Qh, Kh, VhT, mp, pr, Ao);
  gemm_out<<<dim3(512), dim3(256), 0, stream>>>(Ao, wt, bo, out);
}

// Round 9
// 60.764 us; speedup vs baseline: 1.4887x; 1.4495x over previous
//
#include <hip/hip_runtime.h>

#define DEV __device__ __forceinline__

typedef __attribute__((ext_vector_type(4))) float f32x4;
typedef __bf16 bf16_t;
typedef __attribute__((ext_vector_type(4))) bf16_t bf16x4;
typedef __attribute__((ext_vector_type(8))) bf16_t bf16x8;
typedef __attribute__((ext_vector_type(8))) unsigned short us8;
typedef __attribute__((ext_vector_type(4))) unsigned short us4;

// B=8, S=2048, D_MODEL=256, H=4, DEPTH=64, BH=32, M=B*S=16384

DEV unsigned short f2bf(float f) {
  bf16_t h = (bf16_t)f;
  return __builtin_bit_cast(unsigned short, h);
}

DEV void gl2lds16(const void* g, void* l) {
  __builtin_amdgcn_global_load_lds(
      (const __attribute__((address_space(1))) unsigned int*)g,
      (__attribute__((address_space(3))) unsigned int*)l, 16, 0, 0);
}

DEV f32x4 mfma16(bf16x8 a, bf16x8 b, f32x4 c) {
  return __builtin_amdgcn_mfma_f32_16x16x32_bf16(a, b, c, 0, 0, 0);
}

// ---- prep: W transpose via LDS (blocks 0..63), mask prescale + prune (block 64) ----
// Pruning: tile t of batch b can influence softmax only if
//   tilemin_mask[t] < running_min + 1.45e-6   (sound bound, |0.18*qk|<=1000)
__global__ __launch_bounds__(256) void prep_w(
    const float* __restrict__ wq, const float* __restrict__ wk,
    const float* __restrict__ wv, const float* __restrict__ wo,
    const float* __restrict__ mask,
    unsigned short* __restrict__ wt, float* __restrict__ mprep,
    int* __restrict__ proc) {
  const int t = threadIdx.x;
  if (blockIdx.x < 64) {
    __shared__ float T[64 * 65];
    const int mat = blockIdx.x >> 4, tn = (blockIdx.x >> 2) & 3, tk = blockIdx.x & 3;
    const int n0 = tn * 64, k0 = tk * 64;
    const float* W = (mat == 0) ? wq : (mat == 1) ? wk : (mat == 2) ? wv : wo;
    const int r0 = t >> 4, c = (t & 15) * 4;
#pragma unroll
    for (int i = 0; i < 4; ++i) {
      int rr = r0 + i * 16;                       // k-local row
      f32x4 x = *(const f32x4*)(W + (k0 + rr) * 256 + n0 + c);
#pragma unroll
      for (int j = 0; j < 4; ++j) T[(c + j) * 65 + rr] = x[j];
    }
    __syncthreads();
#pragma unroll
    for (int i = 0; i < 2; ++i) {
      int u = t + i * 256;
      int n = u >> 3, seg = u & 7;
      us8 pk;
#pragma unroll
      for (int j = 0; j < 8; ++j) pk[j] = f2bf(T[n * 65 + seg * 8 + j]);
      *(us8*)(&wt[mat * 65536 + (n0 + n) * 256 + k0 + seg * 8]) = pk;
    }
  } else {
    __shared__ float tm[256];
    const float* mr = mask + t * 64;
    float mn = 1e30f;
#pragma unroll
    for (int j = 0; j < 16; ++j) {
      f32x4 x = *(const f32x4*)(mr + j * 4);
      mn = fminf(mn, fminf(fminf(x[0], x[1]), fminf(x[2], x[3])));
      *(f32x4*)(mprep + t * 64 + j * 4) = x * -1.442695041e9f;
    }
    tm[t] = mn;
    __syncthreads();
    if (t < 8) {
      int base = t * 33, cnt = 0;
      float minm = 1e30f;
      for (int tl = 0; tl < 32; ++tl) {
        float v = tm[t * 32 + tl];
        if (v < minm + 1.45e-6f) { proc[base + 1 + cnt] = tl; ++cnt; }
        minm = fminf(minm, v);
      }
      proc[base] = cnt;
    }
  }
}

// ---- QKV projection: M64 x N256(full) x BK64, 8 waves, dbuf, 1 barrier/step ----
// A read exactly once from HBM; W (128 KB bf16) stays L2-resident.
__global__ __launch_bounds__(512, 4) void gemm_qkv(
    const float* __restrict__ Aq, const float* __restrict__ Ak, const float* __restrict__ Av,
    const float* __restrict__ bq, const float* __restrict__ bk, const float* __restrict__ bv,
    const unsigned short* __restrict__ wt,
    unsigned short* __restrict__ Qh, unsigned short* __restrict__ Kh,
    unsigned short* __restrict__ VhT) {
  __shared__ __align__(16) unsigned short At[2][64 * 64];
  __shared__ __align__(16) unsigned short Bt[2][256 * 64];
  const int p = blockIdx.y;
  const float* A    = (p == 0) ? Aq : (p == 1) ? Ak : Av;
  const float* bias = (p == 0) ? bq : (p == 1) ? bk : bv;
  const unsigned short* WT = wt + p * 65536;
  const int t = threadIdx.x, lane = t & 63, wvi = t >> 6;   // 8 waves
  const int lr = lane & 15, lg = lane >> 4;
  const int lx = lr & 7;
  const int m0 = blockIdx.x * 64;

  // A staging: thread t covers row=t>>3 (0..63), seg=t&7 (8 f32)
  const int as_row = t >> 3, as_seg = t & 7;
  const float* agp = A + (m0 + as_row) * 256 + as_seg * 8;

  f32x4 ar0, ar1;
  f32x4 acc[4][2] = {};

#define ISSUE_A(k0)                                                           \
  { ar0 = *(const f32x4*)(agp + (k0));                                        \
    ar1 = *(const f32x4*)(agp + (k0) + 4); }
#define WRITE_A(buf)                                                          \
  { us8 pk;                                                                   \
    _Pragma("unroll") for (int j = 0; j < 4; ++j) {                           \
      pk[j] = f2bf(ar0[j]); pk[j + 4] = f2bf(ar1[j]); }                       \
    *(us8*)(&At[buf][(as_row << 6) + ((as_seg ^ (as_row & 7)) << 3)]) = pk; }
#define STAGE_B(buf, k0)                                                      \
  { _Pragma("unroll") for (int i = 0; i < 4; ++i) {                           \
      int u = t + i * 512;                                                    \
      int row = u >> 3, g = (u & 7) ^ (row & 7);                              \
      gl2lds16(WT + row * 256 + (k0) + g * 8, &Bt[buf][u * 8]); } }

  ISSUE_A(0)
  STAGE_B(0, 0)
  WRITE_A(0)
  __syncthreads();
  int cur = 0;

  for (int j = 0; j < 4; ++j) {
    if (j < 3) { ISSUE_A((j + 1) * 64) STAGE_B(cur ^ 1, (j + 1) * 64) }
#pragma unroll
    for (int ds = 0; ds < 2; ++ds) {
      const int kk = (ds << 2) | lg;
      bf16x8 af[4], bfr[2];
#pragma unroll
      for (int m = 0; m < 4; ++m)
        af[m] = *(const bf16x8*)(&At[cur][((m * 16 + lr) << 6) + ((kk ^ lx) << 3)]);
#pragma unroll
      for (int n = 0; n < 2; ++n)
        bfr[n] = *(const bf16x8*)(&Bt[cur][((wvi * 32 + n * 16 + lr) << 6) + ((kk ^ lx) << 3)]);
#pragma unroll
      for (int m = 0; m < 4; ++m)
#pragma unroll
        for (int n = 0; n < 2; ++n)
          acc[m][n] = mfma16(af[m], bfr[n], acc[m][n]);
    }
    if (j < 3) WRITE_A(cur ^ 1)
    __syncthreads();
    cur ^= 1;
  }
#undef ISSUE_A
#undef WRITE_A
#undef STAGE_B

  const int b = m0 >> 11, s0 = m0 & 2047;
#pragma unroll
  for (int cg = 0; cg < 2; ++cg) {
    int col = wvi * 32 + cg * 16 + lr;
    float bb = bias[col];
    int h = col >> 6, d = col & 63;
    int bh = b * 4 + h;
#pragma unroll
    for (int m = 0; m < 4; ++m) {
      int sb = s0 + m * 16 + lg * 4;
      if (p == 2) {
        us4 o;
#pragma unroll
        for (int r = 0; r < 4; ++r) o[r] = f2bf(acc[m][cg][r] + bb);
        *(us4*)(&VhT[(bh * 64 + d) * 2048 + sb]) = o;
      } else {
        unsigned short* Cp = (p == 0) ? Qh : Kh;
#pragma unroll
        for (int r = 0; r < 4; ++r)
          Cp[(bh * 2048 + sb + r) * 64 + d] = f2bf(acc[m][cg][r] + bb);
      }
    }
  }
}

// ---- fused flash attention: pruned tile list, swapped QK^T, in-register P ----
__global__ __launch_bounds__(256) void attn(
    const unsigned short* __restrict__ Qh, const unsigned short* __restrict__ Kh,
    const unsigned short* __restrict__ VhT, const float* __restrict__ mprep,
    const int* __restrict__ proc,
    unsigned short* __restrict__ Aout) {
  __shared__ __align__(16) unsigned short Kt[2][4096];
  __shared__ __align__(16) unsigned short Vt[2][4096];
  const int bh = blockIdx.y;
  const int q0 = blockIdx.x * 64;
  const int t = threadIdx.x, lane = t & 63, wid = t >> 6;
  const int lr = lane & 15, lg = lane >> 4;
  const int qrow = q0 + wid * 16;
  const unsigned short* Kbase = Kh + bh * 131072;
  const unsigned short* Vbase = VhT + bh * 131072;
  const float* mrow = mprep + (bh >> 2) * 2048;
  const int* plist = proc + (bh >> 2) * 33;
  const int lx = lr & 7;          // swizzle xor
  const int lgh = lg >> 1, lgo = (lg & 1) * 4;

  bf16x8 qf[2];
#pragma unroll
  for (int ds = 0; ds < 2; ++ds)
    qf[ds] = *(const bf16x8*)(Qh + (bh * 2048 + qrow + lr) * 64 + ds * 32 + lg * 8);

  f32x4 accO[4] = {};           // accO[db][r] = O[q=lr][d=db*16+lg*4+r]
  float mrun = -3.0e38f, lrun = 0.f;

#define STAGE(buf, kv)                                                        \
  {                                                                           \
    _Pragma("unroll")                                                         \
    for (int i = 0; i < 2; ++i) {                                             \
      int u = t + i * 256;                                                    \
      int row = u >> 3, g = (u & 7) ^ (row & 7);                              \
      gl2lds16(Kbase + ((kv) + row) * 64 + g * 8, &Kt[buf][u * 8]);           \
      gl2lds16(Vbase + row * 2048 + (kv) + g * 8, &Vt[buf][u * 8]);           \
    }                                                                         \
  }

  const int cnt = plist[0];                 // block-uniform
  STAGE(0, plist[1] * 64)
  __syncthreads();
  int cur = 0;

  for (int j = 0; j < cnt; ++j) {
    const int kv0 = plist[1 + j] * 64;
    if (j + 1 < cnt) STAGE(cur ^ 1, plist[2 + j] * 64)

    // S^T = K Q^T : accS[kb][r] = S[q=lr][k = kv0 + kb*16 + lg*4 + r]
    f32x4 accS[4] = {};
    __builtin_amdgcn_s_setprio(1);
#pragma unroll
    for (int kb = 0; kb < 4; ++kb)
#pragma unroll
      for (int ds = 0; ds < 2; ++ds) {
        bf16x8 kf = *(const bf16x8*)(&Kt[cur][((kb * 16 + lr) << 3 | (((ds << 2) | lg) ^ lx)) * 8]);
        accS[kb] = mfma16(kf, qf[ds], accS[kb]);
      }
    __builtin_amdgcn_s_setprio(0);

    // logits in log2 domain (per-lane row q=lr)
    f32x4 sv[4];
#pragma unroll
    for (int kb = 0; kb < 4; ++kb) {
      f32x4 mk = *(const f32x4*)(mrow + kv0 + kb * 16 + lg * 4);
      sv[kb] = accS[kb] * 0.1803368801f + mk;
    }
    float mx0 = fmaxf(fmaxf(sv[0][0], sv[0][1]), fmaxf(sv[0][2], sv[0][3]));
    float mx1 = fmaxf(fmaxf(sv[1][0], sv[1][1]), fmaxf(sv[1][2], sv[1][3]));
    float mx2 = fmaxf(fmaxf(sv[2][0], sv[2][1]), fmaxf(sv[2][2], sv[2][3]));
    float mx3 = fmaxf(fmaxf(sv[3][0], sv[3][1]), fmaxf(sv[3][2], sv[3][3]));
    float mx = fmaxf(fmaxf(mx0, mx1), fmaxf(mx2, mx3));
    mx = fmaxf(mx, __shfl_xor(mx, 16));
    mx = fmaxf(mx, __shfl_xor(mx, 32));
    float mnew = fmaxf(mrun, mx);
    float al = __builtin_amdgcn_exp2f(mrun - mnew);
    mrun = mnew;

    float px[4][4];
    float lsum = 0.f;
#pragma unroll
    for (int kb = 0; kb < 4; ++kb) {
      float s = 0.f;
#pragma unroll
      for (int r = 0; r < 4; ++r) {
        px[kb][r] = __builtin_amdgcn_exp2f(sv[kb][r] - mnew);
        s += px[kb][r];
      }
      lsum += s;
    }
    lsum += __shfl_xor(lsum, 16);
    lsum += __shfl_xor(lsum, 32);
    lrun = lrun * al + lsum;
#pragma unroll
    for (int db = 0; db < 4; ++db) accO[db] *= al;

    // P fragments, fully lane-local (k-permutation matched by V reads)
    bf16x8 pf[2];
#pragma unroll
    for (int ks = 0; ks < 2; ++ks) {
      bf16x8 p;
#pragma unroll
      for (int r = 0; r < 4; ++r) {
        p[r]     = (bf16_t)px[2 * ks][r];
        p[r + 4] = (bf16_t)px[2 * ks + 1][r];
      }
      pf[ks] = p;
    }

    // O^T += V^T P^T   (A = V^T rows d, k permuted; B = pf)
    __builtin_amdgcn_s_setprio(1);
#pragma unroll
    for (int ks = 0; ks < 2; ++ks)
#pragma unroll
      for (int db = 0; db < 4; ++db) {
        int row = db * 16 + lr;
        int u0 = (row << 3) | (((ks << 2) | lgh) ^ lx);
        int u1 = (row << 3) | (((ks << 2) | 2 | lgh) ^ lx);
        bf16x4 v0 = *(const bf16x4*)(&Vt[cur][u0 * 8 + lgo]);
        bf16x4 v1 = *(const bf16x4*)(&Vt[cur][u1 * 8 + lgo]);
        bf16x8 vf = __builtin_shufflevector(v0, v1, 0, 1, 2, 3, 4, 5, 6, 7);
        accO[db] = mfma16(vf, pf[ks], accO[db]);
      }
    __builtin_amdgcn_s_setprio(0);

    __syncthreads();   // drains prefetch vmcnt + releases cur buf
    cur ^= 1;
  }
#undef STAGE

  const int b = bh >> 2, h = bh & 3;
  const float inv = __builtin_amdgcn_rcpf(lrun);
  const int q = qrow + lr;
#pragma unroll
  for (int db = 0; db < 4; ++db) {
    us4 o;
#pragma unroll
    for (int r = 0; r < 4; ++r) o[r] = f2bf(accO[db][r] * inv);
    *(us4*)(&Aout[(b * 2048 + q) * 256 + h * 64 + db * 16 + lg * 4]) = o;
  }
}

// ---- output projection: M64 x N256(full) x BK64, 8 waves, dbuf gl2lds ----
__global__ __launch_bounds__(512, 4) void gemm_out(
    const unsigned short* __restrict__ Aout, const unsigned short* __restrict__ wt,
    const float* __restrict__ bo, float* __restrict__ out) {
  __shared__ __align__(16) unsigned short At[2][64 * 64];
  __shared__ __align__(16) unsigned short Bt[2][256 * 64];
  const unsigned short* WT = wt + 3 * 65536;
  const int t = threadIdx.x, lane = t & 63, wvi = t >> 6;
  const int lr = lane & 15, lg = lane >> 4;
  const int lx = lr & 7;
  const int m0 = blockIdx.x * 64;

  f32x4 acc[4][2] = {};

#define STAGE_O(buf, k0)                                                      \
  { { int u = t;                                                              \
      int row = u >> 3, g = (u & 7) ^ (row & 7);                              \
      gl2lds16(Aout + (m0 + row) * 256 + (k0) + g * 8, &At[buf][u * 8]); }    \
    _Pragma("unroll") for (int i = 0; i < 4; ++i) {                           \
      int u = t + i * 512;                                                    \
      int row = u >> 3, g = (u & 7) ^ (row & 7);                              \
      gl2lds16(WT + row * 256 + (k0) + g * 8, &Bt[buf][u * 8]); } }

  STAGE_O(0, 0)
  __syncthreads();
  int cur = 0;

  for (int j = 0; j < 4; ++j) {
    if (j < 3) STAGE_O(cur ^ 1, (j + 1) * 64)
#pragma unroll
    for (int ds = 0; ds < 2; ++ds) {
      const int kk = (ds << 2) | lg;
      bf16x8 af[4], bfr[2];
#pragma unroll
      for (int m = 0; m < 4; ++m)
        af[m] = *(const bf16x8*)(&At[cur][((m * 16 + lr) << 6) + ((kk ^ lx) << 3)]);
#pragma unroll
      for (int n = 0; n < 2; ++n)
        bfr[n] = *(const bf16x8*)(&Bt[cur][((wvi * 32 + n * 16 + lr) << 6) + ((kk ^ lx) << 3)]);
#pragma unroll
      for (int m = 0; m < 4; ++m)
#pragma unroll
        for (int n = 0; n < 2; ++n)
          acc[m][n] = mfma16(af[m], bfr[n], acc[m][n]);
    }
    __syncthreads();
    cur ^= 1;
  }
#undef STAGE_O

#pragma unroll
  for (int cg = 0; cg < 2; ++cg) {
    int col = wvi * 32 + cg * 16 + lr;
    float bb = bo[col];
#pragma unroll
    for (int m = 0; m < 4; ++m) {
      int rowb = m0 + m * 16 + lg * 4;
#pragma unroll
      for (int r = 0; r < 4; ++r)
        out[(rowb + r) * 256 + col] = acc[m][cg][r] + bb;
    }
  }
}

extern "C" void kernel_launch(void* const* d_in, const int* in_sizes, int n_in,
                              void* d_out, int out_size, void* d_ws, size_t ws_size,
                              hipStream_t stream) {
  const float* v    = (const float*)d_in[0];
  const float* k    = (const float*)d_in[1];
  const float* q    = (const float*)d_in[2];
  const float* mask = (const float*)d_in[3];
  const float* wq   = (const float*)d_in[4];
  const float* bq   = (const float*)d_in[5];
  const float* wk   = (const float*)d_in[6];
  const float* bk   = (const float*)d_in[7];
  const float* wv   = (const float*)d_in[8];
  const float* bv   = (const float*)d_in[9];
  const float* wo   = (const float*)d_in[10];
  const float* bo   = (const float*)d_in[11];
  float* out = (float*)d_out;
  char* ws = (char*)d_ws;

  // ws: wt 524288 | mprep 65536 | proc 4096 | Qh | Kh | VhT | Aout (8 MB each)
  unsigned short* wt  = (unsigned short*)(ws);
  float*          mp  = (float*)(ws + 524288);
  int*            pr  = (int*)(ws + 589824);
  unsigned short* Qh  = (unsigned short*)(ws + 593920);
  unsigned short* Kh  = (unsigned short*)(ws + 593920 + 8388608);
  unsigned short* VhT = (unsigned short*)(ws + 593920 + 2 * 8388608);
  unsigned short* Ao  = (unsigned short*)(ws + 593920 + 3 * 8388608);

  prep_w<<<dim3(65), dim3(256), 0, stream>>>(wq, wk, wv, wo, mask, wt, mp, pr);
  gemm_qkv<<<dim3(256, 3), dim3(512), 0, stream>>>(q, k, v, bq, bk, bv, wt, Qh, Kh, VhT);
  attn<<<dim3(32, 32), dim3(256), 0, stream>>>(Qh, Kh, VhT, mp, pr, Ao);
  gemm_out<<<dim3(256), dim3(512), 0, stream>>>(Ao, wt, bo, out);
}

// Round 10
// 57.880 us; speedup vs baseline: 1.5629x; 1.0498x over previous
//
#include <hip/hip_runtime.h>

#define DEV __device__ __forceinline__

typedef __attribute__((ext_vector_type(4))) float f32x4;
typedef __bf16 bf16_t;
typedef __attribute__((ext_vector_type(4))) bf16_t bf16x4;
typedef __attribute__((ext_vector_type(8))) bf16_t bf16x8;
typedef __attribute__((ext_vector_type(8))) unsigned short us8;
typedef __attribute__((ext_vector_type(4))) unsigned short us4;

// B=8, S=2048, D_MODEL=256, H=4, DEPTH=64, BH=32, M=B*S=16384

DEV unsigned short f2bf(float f) {
  bf16_t h = (bf16_t)f;
  return __builtin_bit_cast(unsigned short, h);
}

DEV void gl2lds16(const void* g, void* l) {
  __builtin_amdgcn_global_load_lds(
      (const __attribute__((address_space(1))) unsigned int*)g,
      (__attribute__((address_space(3))) unsigned int*)l, 16, 0, 0);
}

DEV f32x4 mfma16(bf16x8 a, bf16x8 b, f32x4 c) {
  return __builtin_amdgcn_mfma_f32_16x16x32_bf16(a, b, c, 0, 0, 0);
}

// ---- prep: W transpose via LDS (blocks 0..63), mask prescale + prune (block 64) ----
// Pruning: tile t of batch b can influence softmax only if
//   tilemin_mask[t] < running_min + 1.45e-6   (sound bound, |0.18*qk|<=1000)
// proc[b*33]: count, proc[b*33+1..]: tile list; proc[512+b*32+tl]: per-tile flag.
__global__ __launch_bounds__(256) void prep_w(
    const float* __restrict__ wq, const float* __restrict__ wk,
    const float* __restrict__ wv, const float* __restrict__ wo,
    const float* __restrict__ mask,
    unsigned short* __restrict__ wt, float* __restrict__ mprep,
    int* __restrict__ proc) {
  const int t = threadIdx.x;
  if (blockIdx.x < 64) {
    __shared__ float T[64 * 65];
    const int mat = blockIdx.x >> 4, tn = (blockIdx.x >> 2) & 3, tk = blockIdx.x & 3;
    const int n0 = tn * 64, k0 = tk * 64;
    const float* W = (mat == 0) ? wq : (mat == 1) ? wk : (mat == 2) ? wv : wo;
    const int r0 = t >> 4, c = (t & 15) * 4;
#pragma unroll
    for (int i = 0; i < 4; ++i) {
      int rr = r0 + i * 16;                       // k-local row
      f32x4 x = *(const f32x4*)(W + (k0 + rr) * 256 + n0 + c);
#pragma unroll
      for (int j = 0; j < 4; ++j) T[(c + j) * 65 + rr] = x[j];
    }
    __syncthreads();
#pragma unroll
    for (int i = 0; i < 2; ++i) {
      int u = t + i * 256;
      int n = u >> 3, seg = u & 7;
      us8 pk;
#pragma unroll
      for (int j = 0; j < 8; ++j) pk[j] = f2bf(T[n * 65 + seg * 8 + j]);
      *(us8*)(&wt[mat * 65536 + (n0 + n) * 256 + k0 + seg * 8]) = pk;
    }
  } else {
    __shared__ float tm[256];
    const float* mr = mask + t * 64;
    float mn = 1e30f;
#pragma unroll
    for (int j = 0; j < 16; ++j) {
      f32x4 x = *(const f32x4*)(mr + j * 4);
      mn = fminf(mn, fminf(fminf(x[0], x[1]), fminf(x[2], x[3])));
      *(f32x4*)(mprep + t * 64 + j * 4) = x * -1.442695041e9f;
    }
    tm[t] = mn;
    __syncthreads();
    if (t < 8) {
      int base = t * 33, cnt = 0;
      float minm = 1e30f;
      for (int tl = 0; tl < 32; ++tl) {
        float v = tm[t * 32 + tl];
        int need = (v < minm + 1.45e-6f) ? 1 : 0;
        proc[512 + t * 32 + tl] = need;
        if (need) { proc[base + 1 + cnt] = tl; ++cnt; }
        minm = fminf(minm, v);
      }
      proc[base] = cnt;
    }
  }
}

// ---- QKV projection: M64 x N256(full) x BK64, 8 waves, dbuf, 1 barrier/step ----
// A read exactly once from HBM; W (128 KB bf16) stays L2-resident.
// K/V blocks for pruned-out tiles early-exit (their output is never read).
__global__ __launch_bounds__(512, 4) void gemm_qkv(
    const float* __restrict__ Aq, const float* __restrict__ Ak, const float* __restrict__ Av,
    const float* __restrict__ bq, const float* __restrict__ bk, const float* __restrict__ bv,
    const unsigned short* __restrict__ wt, const int* __restrict__ proc,
    unsigned short* __restrict__ Qh, unsigned short* __restrict__ Kh,
    unsigned short* __restrict__ VhT) {
  const int p = blockIdx.y;
  if (p != 0 && proc[512 + blockIdx.x] == 0) return;   // block-uniform, pre-barrier

  __shared__ __align__(16) unsigned short At[2][64 * 64];
  __shared__ __align__(16) unsigned short Bt[2][256 * 64];
  const float* A    = (p == 0) ? Aq : (p == 1) ? Ak : Av;
  const float* bias = (p == 0) ? bq : (p == 1) ? bk : bv;
  const unsigned short* WT = wt + p * 65536;
  const int t = threadIdx.x, lane = t & 63, wvi = t >> 6;   // 8 waves
  const int lr = lane & 15, lg = lane >> 4;
  const int lx = lr & 7;
  const int m0 = blockIdx.x * 64;

  // A staging: thread t covers row=t>>3 (0..63), seg=t&7 (8 f32)
  const int as_row = t >> 3, as_seg = t & 7;
  const float* agp = A + (m0 + as_row) * 256 + as_seg * 8;

  f32x4 ar0, ar1;
  f32x4 acc[4][2] = {};

#define ISSUE_A(k0)                                                           \
  { ar0 = *(const f32x4*)(agp + (k0));                                        \
    ar1 = *(const f32x4*)(agp + (k0) + 4); }
#define WRITE_A(buf)                                                          \
  { us8 pk;                                                                   \
    _Pragma("unroll") for (int j = 0; j < 4; ++j) {                           \
      pk[j] = f2bf(ar0[j]); pk[j + 4] = f2bf(ar1[j]); }                       \
    *(us8*)(&At[buf][(as_row << 6) + ((as_seg ^ (as_row & 7)) << 3)]) = pk; }
#define STAGE_B(buf, k0)                                                      \
  { _Pragma("unroll") for (int i = 0; i < 4; ++i) {                           \
      int u = t + i * 512;                                                    \
      int row = u >> 3, g = (u & 7) ^ (row & 7);                              \
      gl2lds16(WT + row * 256 + (k0) + g * 8, &Bt[buf][u * 8]); } }

  ISSUE_A(0)
  STAGE_B(0, 0)
  WRITE_A(0)
  __syncthreads();
  int cur = 0;

  for (int j = 0; j < 4; ++j) {
    if (j < 3) { ISSUE_A((j + 1) * 64) STAGE_B(cur ^ 1, (j + 1) * 64) }
#pragma unroll
    for (int ds = 0; ds < 2; ++ds) {
      const int kk = (ds << 2) | lg;
      bf16x8 af[4], bfr[2];
#pragma unroll
      for (int m = 0; m < 4; ++m)
        af[m] = *(const bf16x8*)(&At[cur][((m * 16 + lr) << 6) + ((kk ^ lx) << 3)]);
#pragma unroll
      for (int n = 0; n < 2; ++n)
        bfr[n] = *(const bf16x8*)(&Bt[cur][((wvi * 32 + n * 16 + lr) << 6) + ((kk ^ lx) << 3)]);
#pragma unroll
      for (int m = 0; m < 4; ++m)
#pragma unroll
        for (int n = 0; n < 2; ++n)
          acc[m][n] = mfma16(af[m], bfr[n], acc[m][n]);
    }
    if (j < 3) WRITE_A(cur ^ 1)
    __syncthreads();
    cur ^= 1;
  }
#undef ISSUE_A
#undef WRITE_A
#undef STAGE_B

  const int b = m0 >> 11, s0 = m0 & 2047;
#pragma unroll
  for (int cg = 0; cg < 2; ++cg) {
    int col = wvi * 32 + cg * 16 + lr;
    float bb = bias[col];
    int h = col >> 6, d = col & 63;
    int bh = b * 4 + h;
#pragma unroll
    for (int m = 0; m < 4; ++m) {
      int sb = s0 + m * 16 + lg * 4;
      if (p == 2) {
        us4 o;
#pragma unroll
        for (int r = 0; r < 4; ++r) o[r] = f2bf(acc[m][cg][r] + bb);
        *(us4*)(&VhT[(bh * 64 + d) * 2048 + sb]) = o;
      } else {
        unsigned short* Cp = (p == 0) ? Qh : Kh;
#pragma unroll
        for (int r = 0; r < 4; ++r)
          Cp[(bh * 2048 + sb + r) * 64 + d] = f2bf(acc[m][cg][r] + bb);
      }
    }
  }
}

// ---- fused flash attention: pruned tile list, swapped QK^T, in-register P ----
__global__ __launch_bounds__(256) void attn(
    const unsigned short* __restrict__ Qh, const unsigned short* __restrict__ Kh,
    const unsigned short* __restrict__ VhT, const float* __restrict__ mprep,
    const int* __restrict__ proc,
    unsigned short* __restrict__ Aout) {
  __shared__ __align__(16) unsigned short Kt[2][4096];
  __shared__ __align__(16) unsigned short Vt[2][4096];
  const int bh = blockIdx.y;
  const int q0 = blockIdx.x * 64;
  const int t = threadIdx.x, lane = t & 63, wid = t >> 6;
  const int lr = lane & 15, lg = lane >> 4;
  const int qrow = q0 + wid * 16;
  const unsigned short* Kbase = Kh + bh * 131072;
  const unsigned short* Vbase = VhT + bh * 131072;
  const float* mrow = mprep + (bh >> 2) * 2048;
  const int* plist = proc + (bh >> 2) * 33;
  const int lx = lr & 7;          // swizzle xor
  const int lgh = lg >> 1, lgo = (lg & 1) * 4;

  bf16x8 qf[2];
#pragma unroll
  for (int ds = 0; ds < 2; ++ds)
    qf[ds] = *(const bf16x8*)(Qh + (bh * 2048 + qrow + lr) * 64 + ds * 32 + lg * 8);

  f32x4 accO[4] = {};           // accO[db][r] = O[q=lr][d=db*16+lg*4+r]
  float mrun = -3.0e38f, lrun = 0.f;

#define STAGE(buf, kv)                                                        \
  {                                                                           \
    _Pragma("unroll")                                                         \
    for (int i = 0; i < 2; ++i) {                                             \
      int u = t + i * 256;                                                    \
      int row = u >> 3, g = (u & 7) ^ (row & 7);                              \
      gl2lds16(Kbase + ((kv) + row) * 64 + g * 8, &Kt[buf][u * 8]);           \
      gl2lds16(Vbase + row * 2048 + (kv) + g * 8, &Vt[buf][u * 8]);           \
    }                                                                         \
  }

  const int cnt = plist[0];                 // block-uniform
  STAGE(0, plist[1] * 64)
  __syncthreads();
  int cur = 0;

  for (int j = 0; j < cnt; ++j) {
    const int kv0 = plist[1 + j] * 64;
    if (j + 1 < cnt) STAGE(cur ^ 1, plist[2 + j] * 64)

    // S^T = K Q^T : accS[kb][r] = S[q=lr][k = kv0 + kb*16 + lg*4 + r]
    f32x4 accS[4] = {};
    __builtin_amdgcn_s_setprio(1);
#pragma unroll
    for (int kb = 0; kb < 4; ++kb)
#pragma unroll
      for (int ds = 0; ds < 2; ++ds) {
        bf16x8 kf = *(const bf16x8*)(&Kt[cur][((kb * 16 + lr) << 3 | (((ds << 2) | lg) ^ lx)) * 8]);
        accS[kb] = mfma16(kf, qf[ds], accS[kb]);
      }
    __builtin_amdgcn_s_setprio(0);

    // logits in log2 domain (per-lane row q=lr)
    f32x4 sv[4];
#pragma unroll
    for (int kb = 0; kb < 4; ++kb) {
      f32x4 mk = *(const f32x4*)(mrow + kv0 + kb * 16 + lg * 4);
      sv[kb] = accS[kb] * 0.1803368801f + mk;
    }
    float mx0 = fmaxf(fmaxf(sv[0][0], sv[0][1]), fmaxf(sv[0][2], sv[0][3]));
    float mx1 = fmaxf(fmaxf(sv[1][0], sv[1][1]), fmaxf(sv[1][2], sv[1][3]));
    float mx2 = fmaxf(fmaxf(sv[2][0], sv[2][1]), fmaxf(sv[2][2], sv[2][3]));
    float mx3 = fmaxf(fmaxf(sv[3][0], sv[3][1]), fmaxf(sv[3][2], sv[3][3]));
    float mx = fmaxf(fmaxf(mx0, mx1), fmaxf(mx2, mx3));
    mx = fmaxf(mx, __shfl_xor(mx, 16));
    mx = fmaxf(mx, __shfl_xor(mx, 32));
    float mnew = fmaxf(mrun, mx);
    float al = __builtin_amdgcn_exp2f(mrun - mnew);
    mrun = mnew;

    float px[4][4];
    float lsum = 0.f;
#pragma unroll
    for (int kb = 0; kb < 4; ++kb) {
      float s = 0.f;
#pragma unroll
      for (int r = 0; r < 4; ++r) {
        px[kb][r] = __builtin_amdgcn_exp2f(sv[kb][r] - mnew);
        s += px[kb][r];
      }
      lsum += s;
    }
    lsum += __shfl_xor(lsum, 16);
    lsum += __shfl_xor(lsum, 32);
    lrun = lrun * al + lsum;
#pragma unroll
    for (int db = 0; db < 4; ++db) accO[db] *= al;

    // P fragments, fully lane-local (k-permutation matched by V reads)
    bf16x8 pf[2];
#pragma unroll
    for (int ks = 0; ks < 2; ++ks) {
      bf16x8 p;
#pragma unroll
      for (int r = 0; r < 4; ++r) {
        p[r]     = (bf16_t)px[2 * ks][r];
        p[r + 4] = (bf16_t)px[2 * ks + 1][r];
      }
      pf[ks] = p;
    }

    // O^T += V^T P^T   (A = V^T rows d, k permuted; B = pf)
    __builtin_amdgcn_s_setprio(1);
#pragma unroll
    for (int ks = 0; ks < 2; ++ks)
#pragma unroll
      for (int db = 0; db < 4; ++db) {
        int row = db * 16 + lr;
        int u0 = (row << 3) | (((ks << 2) | lgh) ^ lx);
        int u1 = (row << 3) | (((ks << 2) | 2 | lgh) ^ lx);
        bf16x4 v0 = *(const bf16x4*)(&Vt[cur][u0 * 8 + lgo]);
        bf16x4 v1 = *(const bf16x4*)(&Vt[cur][u1 * 8 + lgo]);
        bf16x8 vf = __builtin_shufflevector(v0, v1, 0, 1, 2, 3, 4, 5, 6, 7);
        accO[db] = mfma16(vf, pf[ks], accO[db]);
      }
    __builtin_amdgcn_s_setprio(0);

    __syncthreads();   // drains prefetch vmcnt + releases cur buf
    cur ^= 1;
  }
#undef STAGE

  const int b = bh >> 2, h = bh & 3;
  const float inv = __builtin_amdgcn_rcpf(lrun);
  const int q = qrow + lr;
#pragma unroll
  for (int db = 0; db < 4; ++db) {
    us4 o;
#pragma unroll
    for (int r = 0; r < 4; ++r) o[r] = f2bf(accO[db][r] * inv);
    *(us4*)(&Aout[(b * 2048 + q) * 256 + h * 64 + db * 16 + lg * 4]) = o;
  }
}

// ---- output projection: M64 x N256(full) x BK64, 8 waves, dbuf gl2lds ----
__global__ __launch_bounds__(512, 4) void gemm_out(
    const unsigned short* __restrict__ Aout, const unsigned short* __restrict__ wt,
    const float* __restrict__ bo, float* __restrict__ out) {
  __shared__ __align__(16) unsigned short At[2][64 * 64];
  __shared__ __align__(16) unsigned short Bt[2][256 * 64];
  const unsigned short* WT = wt + 3 * 65536;
  const int t = threadIdx.x, lane = t & 63, wvi = t >> 6;
  const int lr = lane & 15, lg = lane >> 4;
  const int lx = lr & 7;
  const int m0 = blockIdx.x * 64;

  f32x4 acc[4][2] = {};

#define STAGE_O(buf, k0)                                                      \
  { { int u = t;                                                              \
      int row = u >> 3, g = (u & 7) ^ (row & 7);                              \
      gl2lds16(Aout + (m0 + row) * 256 + (k0) + g * 8, &At[buf][u * 8]); }    \
    _Pragma("unroll") for (int i = 0; i < 4; ++i) {                           \
      int u = t + i * 512;                                                    \
      int row = u >> 3, g = (u & 7) ^ (row & 7);                              \
      gl2lds16(WT + row * 256 + (k0) + g * 8, &Bt[buf][u * 8]); } }

  STAGE_O(0, 0)
  __syncthreads();
  int cur = 0;

  for (int j = 0; j < 4; ++j) {
    if (j < 3) STAGE_O(cur ^ 1, (j + 1) * 64)
#pragma unroll
    for (int ds = 0; ds < 2; ++ds) {
      const int kk = (ds << 2) | lg;
      bf16x8 af[4], bfr[2];
#pragma unroll
      for (int m = 0; m < 4; ++m)
        af[m] = *(const bf16x8*)(&At[cur][((m * 16 + lr) << 6) + ((kk ^ lx) << 3)]);
#pragma unroll
      for (int n = 0; n < 2; ++n)
        bfr[n] = *(const bf16x8*)(&Bt[cur][((wvi * 32 + n * 16 + lr) << 6) + ((kk ^ lx) << 3)]);
#pragma unroll
      for (int m = 0; m < 4; ++m)
#pragma unroll
        for (int n = 0; n < 2; ++n)
          acc[m][n] = mfma16(af[m], bfr[n], acc[m][n]);
    }
    __syncthreads();
    cur ^= 1;
  }
#undef STAGE_O

#pragma unroll
  for (int cg = 0; cg < 2; ++cg) {
    int col = wvi * 32 + cg * 16 + lr;
    float bb = bo[col];
#pragma unroll
    for (int m = 0; m < 4; ++m) {
      int rowb = m0 + m * 16 + lg * 4;
#pragma unroll
      for (int r = 0; r < 4; ++r)
        out[(rowb + r) * 256 + col] = acc[m][cg][r] + bb;
    }
  }
}

extern "C" void kernel_launch(void* const* d_in, const int* in_sizes, int n_in,
                              void* d_out, int out_size, void* d_ws, size_t ws_size,
                              hipStream_t stream) {
  const float* v    = (const float*)d_in[0];
  const float* k    = (const float*)d_in[1];
  const float* q    = (const float*)d_in[2];
  const float* mask = (const float*)d_in[3];
  const float* wq   = (const float*)d_in[4];
  const float* bq   = (const float*)d_in[5];
  const float* wk   = (const float*)d_in[6];
  const float* bk   = (const float*)d_in[7];
  const float* wv   = (const float*)d_in[8];
  const float* bv   = (const float*)d_in[9];
  const float* wo   = (const float*)d_in[10];
  const float* bo   = (const float*)d_in[11];
  float* out = (float*)d_out;
  char* ws = (char*)d_ws;

  // ws: wt 524288 | mprep 65536 | proc 4096 | Qh | Kh | VhT | Aout (8 MB each)
  unsigned short* wt  = (unsigned short*)(ws);
  float*          mp  = (float*)(ws + 524288);
  int*            pr  = (int*)(ws + 589824);
  unsigned short* Qh  = (unsigned short*)(ws + 593920);
  unsigned short* Kh  = (unsigned short*)(ws + 593920 + 8388608);
  unsigned short* VhT = (unsigned short*)(ws + 593920 + 2 * 8388608);
  unsigned short* Ao  = (unsigned short*)(ws + 593920 + 3 * 8388608);

  prep_w<<<dim3(65), dim3(256), 0, stream>>>(wq, wk, wv, wo, mask, wt, mp, pr);
  gemm_qkv<<<dim3(256, 3), dim3(512), 0, stream>>>(q, k, v, bq, bk, bv, wt, pr, Qh, Kh, VhT);
  attn<<<dim3(32, 32), dim3(256), 0, stream>>>(Qh, Kh, VhT, mp, pr, Ao);
  gemm_out<<<dim3(256), dim3(512), 0, stream>>>(Ao, wt, bo, out);
}

// Round 11
// 57.014 us; speedup vs baseline: 1.5867x; 1.0152x over previous
//
#include <hip/hip_runtime.h>

#define DEV __device__ __forceinline__

typedef __attribute__((ext_vector_type(4))) float f32x4;
typedef __bf16 bf16_t;
typedef __attribute__((ext_vector_type(4))) bf16_t bf16x4;
typedef __attribute__((ext_vector_type(8))) bf16_t bf16x8;
typedef __attribute__((ext_vector_type(8))) unsigned short us8;
typedef __attribute__((ext_vector_type(4))) unsigned short us4;

// B=8, S=2048, D_MODEL=256, H=4, DEPTH=64, BH=32, M=B*S=16384

DEV unsigned short f2bf(float f) {
  bf16_t h = (bf16_t)f;
  return __builtin_bit_cast(unsigned short, h);
}

DEV void gl2lds16(const void* g, void* l) {
  __builtin_amdgcn_global_load_lds(
      (const __attribute__((address_space(1))) unsigned int*)g,
      (__attribute__((address_space(3))) unsigned int*)l, 16, 0, 0);
}

DEV f32x4 mfma16(bf16x8 a, bf16x8 b, f32x4 c) {
  return __builtin_amdgcn_mfma_f32_16x16x32_bf16(a, b, c, 0, 0, 0);
}

// ---- prep: W transpose (blocks 0..63); per-batch mask prescale+prune (64..71) ----
// Pruning: tile t of batch b can influence softmax only if
//   tilemin_mask[t] < running_min + 1.45e-6   (sound bound, |0.18*qk|<=1000)
// proc[b*33]: count, +1..: tile list; proc[512+b*32+tl]: per-tile need flag.
__global__ __launch_bounds__(256) void prep_w(
    const float* __restrict__ wq, const float* __restrict__ wk,
    const float* __restrict__ wv, const float* __restrict__ wo,
    const float* __restrict__ mask,
    unsigned short* __restrict__ wt, float* __restrict__ mprep,
    int* __restrict__ proc) {
  const int t = threadIdx.x;
  if (blockIdx.x < 64) {
    __shared__ float T[64 * 65];
    const int mat = blockIdx.x >> 4, tn = (blockIdx.x >> 2) & 3, tk = blockIdx.x & 3;
    const int n0 = tn * 64, k0 = tk * 64;
    const float* W = (mat == 0) ? wq : (mat == 1) ? wk : (mat == 2) ? wv : wo;
    const int r0 = t >> 4, c = (t & 15) * 4;
#pragma unroll
    for (int i = 0; i < 4; ++i) {
      int rr = r0 + i * 16;                       // k-local row
      f32x4 x = *(const f32x4*)(W + (k0 + rr) * 256 + n0 + c);
#pragma unroll
      for (int j = 0; j < 4; ++j) T[(c + j) * 65 + rr] = x[j];
    }
    __syncthreads();
#pragma unroll
    for (int i = 0; i < 2; ++i) {
      int u = t + i * 256;
      int n = u >> 3, seg = u & 7;
      us8 pk;
#pragma unroll
      for (int j = 0; j < 8; ++j) pk[j] = f2bf(T[n * 65 + seg * 8 + j]);
      *(us8*)(&wt[mat * 65536 + (n0 + n) * 256 + k0 + seg * 8]) = pk;
    }
  } else {
    __shared__ float tm[32];
    const int b = blockIdx.x - 64;
    const float* mr = mask + b * 2048;
    f32x4 x0 = *(const f32x4*)(mr + t * 8);
    f32x4 x1 = *(const f32x4*)(mr + t * 8 + 4);
    *(f32x4*)(mprep + b * 2048 + t * 8)     = x0 * -1.442695041e9f;
    *(f32x4*)(mprep + b * 2048 + t * 8 + 4) = x1 * -1.442695041e9f;
    float mn = fminf(fminf(fminf(x0[0], x0[1]), fminf(x0[2], x0[3])),
                     fminf(fminf(x1[0], x1[1]), fminf(x1[2], x1[3])));
    mn = fminf(mn, __shfl_xor(mn, 1));
    mn = fminf(mn, __shfl_xor(mn, 2));
    mn = fminf(mn, __shfl_xor(mn, 4));
    if ((t & 7) == 0) tm[t >> 3] = mn;
    __syncthreads();
    if (t == 0) {
      int base = b * 33, cnt = 0;
      float minm = 1e30f;
      for (int tl = 0; tl < 32; ++tl) {
        float v = tm[tl];
        int need = (v < minm + 1.45e-6f) ? 1 : 0;
        proc[512 + b * 32 + tl] = need;
        if (need) { proc[base + 1 + cnt] = tl; ++cnt; }
        minm = fminf(minm, v);
      }
      proc[base] = cnt;
    }
  }
}

// ---- QKV projection: SINGLE-PHASE. Full K=256 in LDS (A 32KB + B 128KB = 160KB),
// one barrier, 64 MFMA/wave straight through. K/V pruned blocks early-exit. ----
__global__ __launch_bounds__(512) void gemm_qkv(
    const float* __restrict__ Aq, const float* __restrict__ Ak, const float* __restrict__ Av,
    const float* __restrict__ bq, const float* __restrict__ bk, const float* __restrict__ bv,
    const unsigned short* __restrict__ wt, const int* __restrict__ proc,
    unsigned short* __restrict__ Qh, unsigned short* __restrict__ Kh,
    unsigned short* __restrict__ VhT) {
  const int p = blockIdx.y;
  if (p != 0 && proc[512 + blockIdx.x] == 0) return;   // block-uniform, pre-barrier

  __shared__ __align__(16) unsigned short At[64 * 256];     // 32 KB
  __shared__ __align__(16) unsigned short Bt[256 * 256];    // 128 KB
  const float* A    = (p == 0) ? Aq : (p == 1) ? Ak : Av;
  const float* bias = (p == 0) ? bq : (p == 1) ? bk : bv;
  const unsigned short* WT = wt + p * 65536;
  const int t = threadIdx.x, lane = t & 63, wvi = t >> 6;   // 8 waves
  const int lr = lane & 15, lg = lane >> 4;
  const int lx = lr & 7;
  const int m0 = blockIdx.x * 64;

  // stage B: 256 rows x 32 us8-units, pre-swizzled global source
#pragma unroll
  for (int i = 0; i < 16; ++i) {
    int u = t + i * 512;
    int row = u >> 5, un = u & 31;
    int g = (un & 24) | ((un & 7) ^ (row & 7));
    gl2lds16(WT + row * 256 + g * 8, &Bt[u * 8]);
  }
  // stage A: f32 -> bf16 via regs, swizzled LDS write
#pragma unroll
  for (int i = 0; i < 4; ++i) {
    int u = t + i * 512;
    int row = u >> 5, un = u & 31;
    const float* src = A + (m0 + row) * 256 + un * 8;
    f32x4 x0 = *(const f32x4*)src;
    f32x4 x1 = *(const f32x4*)(src + 4);
    us8 pk;
#pragma unroll
    for (int j = 0; j < 4; ++j) { pk[j] = f2bf(x0[j]); pk[j + 4] = f2bf(x1[j]); }
    *(us8*)(&At[row * 256 + (((un & 24) | ((un & 7) ^ (row & 7))) << 3)]) = pk;
  }
  __syncthreads();

  f32x4 acc[4][2] = {};
#pragma unroll
  for (int ds = 0; ds < 8; ++ds) {
    const int ku = ds * 4 + lg;
    const int phys = ((ku & 24) | ((ku & 7) ^ lx)) << 3;
    bf16x8 af[4], bfr[2];
#pragma unroll
    for (int m = 0; m < 4; ++m)
      af[m] = *(const bf16x8*)(&At[(m * 16 + lr) * 256 + phys]);
#pragma unroll
    for (int n = 0; n < 2; ++n)
      bfr[n] = *(const bf16x8*)(&Bt[(wvi * 32 + n * 16 + lr) * 256 + phys]);
#pragma unroll
    for (int m = 0; m < 4; ++m)
#pragma unroll
      for (int n = 0; n < 2; ++n)
        acc[m][n] = mfma16(af[m], bfr[n], acc[m][n]);
  }

  const int b = m0 >> 11, s0 = m0 & 2047;
#pragma unroll
  for (int cg = 0; cg < 2; ++cg) {
    int col = wvi * 32 + cg * 16 + lr;
    float bb = bias[col];
    int h = col >> 6, d = col & 63;
    int bh = b * 4 + h;
#pragma unroll
    for (int m = 0; m < 4; ++m) {
      int sb = s0 + m * 16 + lg * 4;
      if (p == 2) {
        us4 o;
#pragma unroll
        for (int r = 0; r < 4; ++r) o[r] = f2bf(acc[m][cg][r] + bb);
        *(us4*)(&VhT[(bh * 64 + d) * 2048 + sb]) = o;
      } else {
        unsigned short* Cp = (p == 0) ? Qh : Kh;
#pragma unroll
        for (int r = 0; r < 4; ++r)
          Cp[(bh * 2048 + sb + r) * 64 + d] = f2bf(acc[m][cg][r] + bb);
      }
    }
  }
}

// ---- fused flash attention: pruned tile list, swapped QK^T, in-register P ----
__global__ __launch_bounds__(256) void attn(
    const unsigned short* __restrict__ Qh, const unsigned short* __restrict__ Kh,
    const unsigned short* __restrict__ VhT, const float* __restrict__ mprep,
    const int* __restrict__ proc,
    unsigned short* __restrict__ Aout) {
  __shared__ __align__(16) unsigned short Kt[2][4096];
  __shared__ __align__(16) unsigned short Vt[2][4096];
  const int bh = blockIdx.y;
  const int q0 = blockIdx.x * 64;
  const int t = threadIdx.x, lane = t & 63, wid = t >> 6;
  const int lr = lane & 15, lg = lane >> 4;
  const int qrow = q0 + wid * 16;
  const unsigned short* Kbase = Kh + bh * 131072;
  const unsigned short* Vbase = VhT + bh * 131072;
  const float* mrow = mprep + (bh >> 2) * 2048;
  const int* plist = proc + (bh >> 2) * 33;
  const int lx = lr & 7;          // swizzle xor
  const int lgh = lg >> 1, lgo = (lg & 1) * 4;

  bf16x8 qf[2];
#pragma unroll
  for (int ds = 0; ds < 2; ++ds)
    qf[ds] = *(const bf16x8*)(Qh + (bh * 2048 + qrow + lr) * 64 + ds * 32 + lg * 8);

  f32x4 accO[4] = {};           // accO[db][r] = O[q=lr][d=db*16+lg*4+r]
  float mrun = -3.0e38f, lrun = 0.f;

#define STAGE(buf, kv)                                                        \
  {                                                                           \
    _Pragma("unroll")                                                         \
    for (int i = 0; i < 2; ++i) {                                             \
      int u = t + i * 256;                                                    \
      int row = u >> 3, g = (u & 7) ^ (row & 7);                              \
      gl2lds16(Kbase + ((kv) + row) * 64 + g * 8, &Kt[buf][u * 8]);           \
      gl2lds16(Vbase + row * 2048 + (kv) + g * 8, &Vt[buf][u * 8]);           \
    }                                                                         \
  }

  const int cnt = plist[0];                 // block-uniform
  STAGE(0, plist[1] * 64)
  __syncthreads();
  int cur = 0;

  for (int j = 0; j < cnt; ++j) {
    const int kv0 = plist[1 + j] * 64;
    if (j + 1 < cnt) STAGE(cur ^ 1, plist[2 + j] * 64)

    // S^T = K Q^T : accS[kb][r] = S[q=lr][k = kv0 + kb*16 + lg*4 + r]
    f32x4 accS[4] = {};
    __builtin_amdgcn_s_setprio(1);
#pragma unroll
    for (int kb = 0; kb < 4; ++kb)
#pragma unroll
      for (int ds = 0; ds < 2; ++ds) {
        bf16x8 kf = *(const bf16x8*)(&Kt[cur][((kb * 16 + lr) << 3 | (((ds << 2) | lg) ^ lx)) * 8]);
        accS[kb] = mfma16(kf, qf[ds], accS[kb]);
      }
    __builtin_amdgcn_s_setprio(0);

    // logits in log2 domain (per-lane row q=lr)
    f32x4 sv[4];
#pragma unroll
    for (int kb = 0; kb < 4; ++kb) {
      f32x4 mk = *(const f32x4*)(mrow + kv0 + kb * 16 + lg * 4);
      sv[kb] = accS[kb] * 0.1803368801f + mk;
    }
    float mx0 = fmaxf(fmaxf(sv[0][0], sv[0][1]), fmaxf(sv[0][2], sv[0][3]));
    float mx1 = fmaxf(fmaxf(sv[1][0], sv[1][1]), fmaxf(sv[1][2], sv[1][3]));
    float mx2 = fmaxf(fmaxf(sv[2][0], sv[2][1]), fmaxf(sv[2][2], sv[2][3]));
    float mx3 = fmaxf(fmaxf(sv[3][0], sv[3][1]), fmaxf(sv[3][2], sv[3][3]));
    float mx = fmaxf(fmaxf(mx0, mx1), fmaxf(mx2, mx3));
    mx = fmaxf(mx, __shfl_xor(mx, 16));
    mx = fmaxf(mx, __shfl_xor(mx, 32));
    float mnew = fmaxf(mrun, mx);
    float al = __builtin_amdgcn_exp2f(mrun - mnew);
    mrun = mnew;

    float px[4][4];
    float lsum = 0.f;
#pragma unroll
    for (int kb = 0; kb < 4; ++kb) {
      float s = 0.f;
#pragma unroll
      for (int r = 0; r < 4; ++r) {
        px[kb][r] = __builtin_amdgcn_exp2f(sv[kb][r] - mnew);
        s += px[kb][r];
      }
      lsum += s;
    }
    lsum += __shfl_xor(lsum, 16);
    lsum += __shfl_xor(lsum, 32);
    lrun = lrun * al + lsum;
#pragma unroll
    for (int db = 0; db < 4; ++db) accO[db] *= al;

    // P fragments, fully lane-local (k-permutation matched by V reads)
    bf16x8 pf[2];
#pragma unroll
    for (int ks = 0; ks < 2; ++ks) {
      bf16x8 p;
#pragma unroll
      for (int r = 0; r < 4; ++r) {
        p[r]     = (bf16_t)px[2 * ks][r];
        p[r + 4] = (bf16_t)px[2 * ks + 1][r];
      }
      pf[ks] = p;
    }

    // O^T += V^T P^T   (A = V^T rows d, k permuted; B = pf)
    __builtin_amdgcn_s_setprio(1);
#pragma unroll
    for (int ks = 0; ks < 2; ++ks)
#pragma unroll
      for (int db = 0; db < 4; ++db) {
        int row = db * 16 + lr;
        int u0 = (row << 3) | (((ks << 2) | lgh) ^ lx);
        int u1 = (row << 3) | (((ks << 2) | 2 | lgh) ^ lx);
        bf16x4 v0 = *(const bf16x4*)(&Vt[cur][u0 * 8 + lgo]);
        bf16x4 v1 = *(const bf16x4*)(&Vt[cur][u1 * 8 + lgo]);
        bf16x8 vf = __builtin_shufflevector(v0, v1, 0, 1, 2, 3, 4, 5, 6, 7);
        accO[db] = mfma16(vf, pf[ks], accO[db]);
      }
    __builtin_amdgcn_s_setprio(0);

    __syncthreads();   // drains prefetch vmcnt + releases cur buf
    cur ^= 1;
  }
#undef STAGE

  const int b = bh >> 2, h = bh & 3;
  const float inv = __builtin_amdgcn_rcpf(lrun);
  const int q = qrow + lr;
#pragma unroll
  for (int db = 0; db < 4; ++db) {
    us4 o;
#pragma unroll
    for (int r = 0; r < 4; ++r) o[r] = f2bf(accO[db][r] * inv);
    *(us4*)(&Aout[(b * 2048 + q) * 256 + h * 64 + db * 16 + lg * 4]) = o;
  }
}

// ---- output projection: SINGLE-PHASE, full K in LDS; LDS-transposed f32x4 out ----
__global__ __launch_bounds__(512) void gemm_out(
    const unsigned short* __restrict__ Aout, const unsigned short* __restrict__ wt,
    const float* __restrict__ bo, float* __restrict__ out) {
  __shared__ __align__(16) unsigned short At[64 * 256];     // 32 KB
  __shared__ __align__(16) unsigned short Bt[256 * 256];    // 128 KB
  const unsigned short* WT = wt + 3 * 65536;
  const int t = threadIdx.x, lane = t & 63, wvi = t >> 6;
  const int lr = lane & 15, lg = lane >> 4;
  const int lx = lr & 7;
  const int m0 = blockIdx.x * 64;

#pragma unroll
  for (int i = 0; i < 16; ++i) {
    int u = t + i * 512;
    int row = u >> 5, un = u & 31;
    int g = (un & 24) | ((un & 7) ^ (row & 7));
    gl2lds16(WT + row * 256 + g * 8, &Bt[u * 8]);
  }
#pragma unroll
  for (int i = 0; i < 4; ++i) {
    int u = t + i * 512;
    int row = u >> 5, un = u & 31;
    int g = (un & 24) | ((un & 7) ^ (row & 7));
    gl2lds16(Aout + (m0 + row) * 256 + g * 8, &At[u * 8]);
  }
  __syncthreads();

  f32x4 acc[4][2] = {};
#pragma unroll
  for (int ds = 0; ds < 8; ++ds) {
    const int ku = ds * 4 + lg;
    const int phys = ((ku & 24) | ((ku & 7) ^ lx)) << 3;
    bf16x8 af[4], bfr[2];
#pragma unroll
    for (int m = 0; m < 4; ++m)
      af[m] = *(const bf16x8*)(&At[(m * 16 + lr) * 256 + phys]);
#pragma unroll
    for (int n = 0; n < 2; ++n)
      bfr[n] = *(const bf16x8*)(&Bt[(wvi * 32 + n * 16 + lr) * 256 + phys]);
#pragma unroll
    for (int m = 0; m < 4; ++m)
#pragma unroll
      for (int n = 0; n < 2; ++n)
        acc[m][n] = mfma16(af[m], bfr[n], acc[m][n]);
  }
  __syncthreads();                       // LDS reads done; reuse Bt for f32 tile

  float* Tout = (float*)Bt;              // [64][260] f32, padded
#pragma unroll
  for (int cg = 0; cg < 2; ++cg) {
    int col = wvi * 32 + cg * 16 + lr;
    float bb = bo[col];
#pragma unroll
    for (int m = 0; m < 4; ++m)
#pragma unroll
      for (int r = 0; r < 4; ++r)
        Tout[(m * 16 + lg * 4 + r) * 260 + col] = acc[m][cg][r] + bb;
  }
  __syncthreads();

  const int row = t >> 3;
#pragma unroll
  for (int i = 0; i < 8; ++i) {
    int c0 = ((t & 7) + i * 8) * 4;
    *(f32x4*)(out + (m0 + row) * 256 + c0) = *(const f32x4*)(&Tout[row * 260 + c0]);
  }
}

extern "C" void kernel_launch(void* const* d_in, const int* in_sizes, int n_in,
                              void* d_out, int out_size, void* d_ws, size_t ws_size,
                              hipStream_t stream) {
  const float* v    = (const float*)d_in[0];
  const float* k    = (const float*)d_in[1];
  const float* q    = (const float*)d_in[2];
  const float* mask = (const float*)d_in[3];
  const float* wq   = (const float*)d_in[4];
  const float* bq   = (const float*)d_in[5];
  const float* wk   = (const float*)d_in[6];
  const float* bk   = (const float*)d_in[7];
  const float* wv   = (const float*)d_in[8];
  const float* bv   = (const float*)d_in[9];
  const float* wo   = (const float*)d_in[10];
  const float* bo   = (const float*)d_in[11];
  float* out = (float*)d_out;
  char* ws = (char*)d_ws;

  // ws: wt 524288 | mprep 65536 | proc 4096 | Qh | Kh | VhT | Aout (8 MB each)
  unsigned short* wt  = (unsigned short*)(ws);
  float*          mp  = (float*)(ws + 524288);
  int*            pr  = (int*)(ws + 589824);
  unsigned short* Qh  = (unsigned short*)(ws + 593920);
  unsigned short* Kh  = (unsigned short*)(ws + 593920 + 8388608);
  unsigned short* VhT = (unsigned short*)(ws + 593920 + 2 * 8388608);
  unsigned short* Ao  = (unsigned short*)(ws + 593920 + 3 * 8388608);

  prep_w<<<dim3(72), dim3(256), 0, stream>>>(wq, wk, wv, wo, mask, wt, mp, pr);
  gemm_qkv<<<dim3(256, 3), dim3(512), 0, stream>>>(q, k, v, bq, bk, bv, wt, pr, Qh, Kh, VhT);
  attn<<<dim3(32, 32), dim3(256), 0, stream>>>(Qh, Kh, VhT, mp, pr, Ao);
  gemm_out<<<dim3(256), dim3(512), 0, stream>>>(Ao, wt, bo, out);
}